// Round 1
// baseline (210.742 us; speedup 1.0000x reference)
//
#include <hip/hip_runtime.h>

typedef unsigned short u16;
typedef __attribute__((ext_vector_type(8))) short bf16x8;     // MFMA A/B frag (8 bf16)
typedef __attribute__((ext_vector_type(4))) float floatx4;    // MFMA C/D frag
typedef __attribute__((ext_vector_type(8))) unsigned short u16x8;
typedef __attribute__((ext_vector_type(4))) unsigned short u16x4;

#define NTOK 4096
#define DDIN 512
#define DDOUT 512
#define NP 8
#define SPLITK 4

__device__ __forceinline__ float b2f(u16 b) {
    union { unsigned int u; float f; } v; v.u = ((unsigned int)b) << 16; return v.f;
}
__device__ __forceinline__ u16 f2b(float f) {
    union { float f; unsigned int u; } v; v.f = f;
    unsigned int r = (v.u + 0x7fffu + ((v.u >> 16) & 1u)) >> 16;
    return (u16)r;
}
__device__ __forceinline__ float sp(float x) {
    return fmaxf(x, 0.f) + __logf(1.f + __expf(-fabsf(x)));
}
__device__ __forceinline__ float sigm(float x) { return 1.f / (1.f + __expf(-x)); }

__device__ __forceinline__ void gld16(const u16* g, u16* l) {
    __builtin_amdgcn_global_load_lds((const __attribute__((address_space(1))) void*)g,
                                     (__attribute__((address_space(3))) void*)l, 16, 0, 0);
}

// weight transform for both phi_raw and raw_weight2 in one launch:
// out[i] = bf16( softplus(in[i])^2 )
__global__ void prep_sqsp2(const float* __restrict__ in1, u16* __restrict__ out1, int n1,
                           const float* __restrict__ in2, u16* __restrict__ out2, int n2) {
    int i = blockIdx.x * 256 + threadIdx.x;
    if (i < n1) {
        float s = sp(in1[i]);
        out1[i] = f2b(s * s);
    } else if (i - n1 < n2) {
        int j = i - n1;
        float s = sp(in2[j]);
        out2[j] = f2b(s * s);
    }
}

// zwT[p][e][c] = zw[p][c][e] + zw[p][c+512][e]
__global__ void prep_zwT(const float* __restrict__ zw, u16* __restrict__ zwT) {
    int p = blockIdx.z;
    int c0 = blockIdx.x * 32, e0 = blockIdx.y * 32;
    __shared__ float tb[32][33];
    int tx = threadIdx.x, ty = threadIdx.y; // 32 x 8
    const float* base = zw + (size_t)p * 1024 * 512;
#pragma unroll
    for (int r = 0; r < 4; ++r) {
        int cl = ty * 4 + r;
        float a = base[(size_t)(c0 + cl) * 512 + e0 + tx];
        float b = base[(size_t)(c0 + cl + 512) * 512 + e0 + tx];
        tb[cl][tx] = a + b;
    }
    __syncthreads();
    u16* outb = zwT + (size_t)p * 512 * 512;
#pragma unroll
    for (int r = 0; r < 4; ++r) {
        int el = ty * 4 + r;
        outb[(size_t)(e0 + el) * 512 + c0 + tx] = f2b(tb[tx][el]);
    }
}

// phi expansion + bf16 copy of x
__global__ void phi_kernel(const float* __restrict__ x, u16* __restrict__ phi,
                           u16* __restrict__ xb) {
    int i = blockIdx.x * 256 + threadIdx.x;
    float xv = x[i];
    xb[i] = f2b(xv);
    u16x8 v;
#pragma unroll
    for (int k = 0; k < 8; ++k) {
        float s = -1.f + (2.f / 7.f) * (float)k;
        v[k] = f2b(sp(xv + s));
    }
    *(u16x8*)(phi + (size_t)i * 8) = v;
}

// ---------------------------------------------------------------------------
// XOR k-group swizzle (bank-conflict fix, gld16-compatible), unchanged from
// the verified version: lane t stages global 16B-group (t&7)^((t>>3)&7) of
// row t>>3, so LDS[r][g] = G[r][g^(r&7)]; fragment reads XOR the k-group
// with (row&7). Remaining duplication is 2-way = free.
//
// NEW this round: both GEMMs move from the serial 2-phase
// (stage -> vmcnt(0) drain -> compute) to a double-buffered prefetch
// pipeline (T3 minimal recipe): issue next K-step's global_load_lds right
// after the barrier, BEFORE the current step's ds_read+MFMA, so the
// compiler's vmcnt(0)-before-barrier drain happens after ~600 cyc of MFMA
// has covered the load latency. 512-thread blocks (8 waves = 2/SIMD) give
// the SIMDs two waves to interleave.
// ---------------------------------------------------------------------------

// GEMM1 partial, split-K=4 (K=1024 per block, 16 BK=64 steps).
// 128x128 tile, 512 threads, waves 2(M)x4(N), dbuf 64 KB LDS, 2 blocks/CU.
// Grid 512 => fully resident in one round. Partials bf16 in d_out scratch.
__launch_bounds__(512, 4)
__global__ void gemm1p(const u16* __restrict__ phi, const u16* __restrict__ wphi,
                       u16* __restrict__ xpart) {
    __shared__ __align__(16) u16 lds[2 * 2 * 8192];   // 64 KB: [buf][A,B][128][64]

    const int id = blockIdx.x;
    const int kc = id & 3;                 // K-chunk
    const int local = id >> 2;             // [0,128)
    const int o0 = (local & 3) * 128;
    const int n0 = (local >> 2) * 128;
    const int kbase = kc * 1024;

    const int t = threadIdx.x;
    const int wave = t >> 6, lane = t & 63;
    const int wm = wave & 1, wn = wave >> 1;        // 2 x 4 wave grid
    const int l15 = lane & 15, quad = lane >> 4;
    const int srow = t >> 3;                        // [0,64)
    const int sgx = ((t & 7) ^ (srow & 7)) * 8;     // swizzled global k-offset

    const u16* gA = phi  + (size_t)(n0 + srow) * 4096 + kbase + sgx;
    const u16* gB = wphi + (size_t)(o0 + srow) * 4096 + kbase + sgx;

    floatx4 acc[4][2];
#pragma unroll
    for (int i = 0; i < 4; ++i)
#pragma unroll
        for (int j = 0; j < 2; ++j) acc[i][j] = {0.f, 0.f, 0.f, 0.f};

    auto STAGE = [&](int b, int k0) {
        u16* L = lds + b * 16384;
#pragma unroll
        for (int c = 0; c < 2; ++c) {
            gld16(gA + k0 + c * 64 * 4096, L + c * 4096 + t * 8);
            gld16(gB + k0 + c * 64 * 4096, L + 8192 + c * 4096 + t * 8);
        }
    };

    STAGE(0, 0);
    for (int it = 0; it < 16; ++it) {
        const int cur = it & 1;
        __syncthreads();                       // buf[cur] loads drained here
        if (it < 15) STAGE(cur ^ 1, (it + 1) * 64);   // prefetch next K-step
        const u16* As = lds + cur * 16384;
        const u16* Bs = As + 8192;
#pragma unroll
        for (int ks = 0; ks < 2; ++ks) {
            bf16x8 a[4], b[2];
#pragma unroll
            for (int s = 0; s < 4; ++s) {
                int ra = wm * 64 + s * 16 + l15;
                a[s] = *(const bf16x8*)(As + ra * 64 + (((ks * 4 + quad) ^ (ra & 7)) * 8));
            }
#pragma unroll
            for (int s = 0; s < 2; ++s) {
                int rb = wn * 32 + s * 16 + l15;
                b[s] = *(const bf16x8*)(Bs + rb * 64 + (((ks * 4 + quad) ^ (rb & 7)) * 8));
            }
#pragma unroll
            for (int sm = 0; sm < 4; ++sm)
#pragma unroll
                for (int sn = 0; sn < 2; ++sn)
                    acc[sm][sn] = __builtin_amdgcn_mfma_f32_16x16x32_bf16(a[sm], b[sn], acc[sm][sn], 0, 0, 0);
        }
    }

    u16* xp = xpart + (size_t)kc * NTOK * DDOUT;
#pragma unroll
    for (int sm = 0; sm < 4; ++sm)
#pragma unroll
        for (int sn = 0; sn < 2; ++sn) {
            int gcol = o0 + wn * 32 + sn * 16 + l15;
#pragma unroll
            for (int r = 0; r < 4; ++r) {
                int grow = n0 + wm * 64 + sm * 16 + quad * 4 + r;
                xp[(size_t)grow * DDOUT + gcol] = f2b(acc[sm][sn][r]);
            }
        }
}

// reduce 4 bf16 partials + phi_bias, expand 8 gated softplus planes -> z0 (bf16)
__global__ void reduce_ep(const u16* __restrict__ xpart, const float* __restrict__ phi_bias,
                          const float* __restrict__ gate_raw, u16* __restrict__ z0) {
    int idx = blockIdx.x * 256 + threadIdx.x;      // 524288 threads, 4 elems each
    int n = idx >> 7;
    int o4 = (idx & 127) * 4;
    size_t base = (size_t)n * DDOUT + o4;
    float s0 = 0.f, s1 = 0.f, s2 = 0.f, s3 = 0.f;
#pragma unroll
    for (int kc = 0; kc < SPLITK; ++kc) {
        u16x4 v = *(const u16x4*)(xpart + (size_t)kc * NTOK * DDOUT + base);
        s0 += b2f(v[0]); s1 += b2f(v[1]); s2 += b2f(v[2]); s3 += b2f(v[3]);
    }
    floatx4 pb = *(const floatx4*)(phi_bias + o4);
    s0 += pb[0]; s1 += pb[1]; s2 += pb[2]; s3 += pb[3];
#pragma unroll
    for (int p = 0; p < NP; ++p) {
        float g = sigm(gate_raw[p]);
        u16x4 v;
        v[0] = f2b(sp(s0 * g)); v[1] = f2b(sp(s1 * g));
        v[2] = f2b(sp(s2 * g)); v[3] = f2b(sp(s3 * g));
        *(u16x4*)(z0 + (size_t)p * NTOK * DDOUT + base) = v;
    }
}

// Fused GEMM2+GEMM3, 128x128 tile, BK=64, dual accumulators, swizzled LDS.
// 512 threads (8 waves 2x4), double-buffered 128 KB LDS, 1 block/CU,
// prefetch pipeline. XCD-pinned: p = blockIdx.x & 7 keeps each plane's
// z0/w2/zwT in one XCD's L2.
__launch_bounds__(512, 2)
__global__ void gemm23(const u16* __restrict__ z0, const u16* __restrict__ w2b,
                       const u16* __restrict__ xb, const u16* __restrict__ zwT,
                       const float* __restrict__ bias2, const float* __restrict__ gate_raw2,
                       const float* __restrict__ output_bias, float* __restrict__ out) {
    __shared__ __align__(16) u16 lds[2 * 4 * 8192];   // 128 KB: [buf][A1,B1,A2,B2][128][64]

    const int id = blockIdx.x;
    const int p = id & 7;
    const int local = id >> 3;                 // [0,128)
    const int e0 = (local & 3) * 128;
    const int n0 = (local >> 2) * 128;

    const int t = threadIdx.x;
    const int wave = t >> 6, lane = t & 63;
    const int wm = wave & 1, wn = wave >> 1;        // 2 x 4 wave grid
    const int l15 = lane & 15, quad = lane >> 4;
    const int srow = t >> 3;                        // [0,64)
    const int sgx = ((t & 7) ^ (srow & 7)) * 8;     // swizzled global k-offset

    const u16* gA1 = z0  + (size_t)p * NTOK * DDOUT + (size_t)(n0 + srow) * 512 + sgx;
    const u16* gB1 = w2b + (size_t)p * DDOUT * DDOUT + (size_t)(e0 + srow) * 512 + sgx;
    const u16* gA2 = xb  + (size_t)(n0 + srow) * 512 + sgx;
    const u16* gB2 = zwT + (size_t)p * DDOUT * DDIN + (size_t)(e0 + srow) * 512 + sgx;

    floatx4 acc1[4][2], acc2[4][2];
#pragma unroll
    for (int i = 0; i < 4; ++i)
#pragma unroll
        for (int j = 0; j < 2; ++j) {
            acc1[i][j] = {0.f, 0.f, 0.f, 0.f};
            acc2[i][j] = {0.f, 0.f, 0.f, 0.f};
        }

    auto STAGE = [&](int b, int k0) {
        u16* L = lds + b * 32768;
#pragma unroll
        for (int c = 0; c < 2; ++c) {
            gld16(gA1 + k0 + c * 64 * 512, L + c * 4096 + t * 8);
            gld16(gB1 + k0 + c * 64 * 512, L + 8192 + c * 4096 + t * 8);
            gld16(gA2 + k0 + c * 64 * 512, L + 16384 + c * 4096 + t * 8);
            gld16(gB2 + k0 + c * 64 * 512, L + 24576 + c * 4096 + t * 8);
        }
    };

    STAGE(0, 0);
    for (int it = 0; it < 8; ++it) {
        const int cur = it & 1;
        __syncthreads();                       // buf[cur] loads drained here
        if (it < 7) STAGE(cur ^ 1, (it + 1) * 64);    // prefetch next K-step
        const u16* A1 = lds + cur * 32768;
        const u16* B1 = A1 + 8192;
        const u16* A2 = A1 + 16384;
        const u16* B2 = A1 + 24576;
#pragma unroll
        for (int ks = 0; ks < 2; ++ks) {
            bf16x8 a1[4], b1[2], a2[4], b2[2];
#pragma unroll
            for (int s = 0; s < 4; ++s) {
                int ra = wm * 64 + s * 16 + l15;
                int ko = ((ks * 4 + quad) ^ (ra & 7)) * 8;
                a1[s] = *(const bf16x8*)(A1 + ra * 64 + ko);
                a2[s] = *(const bf16x8*)(A2 + ra * 64 + ko);
            }
#pragma unroll
            for (int s = 0; s < 2; ++s) {
                int rb = wn * 32 + s * 16 + l15;
                int ko = ((ks * 4 + quad) ^ (rb & 7)) * 8;
                b1[s] = *(const bf16x8*)(B1 + rb * 64 + ko);
                b2[s] = *(const bf16x8*)(B2 + rb * 64 + ko);
            }
#pragma unroll
            for (int sm = 0; sm < 4; ++sm)
#pragma unroll
                for (int sn = 0; sn < 2; ++sn) {
                    acc1[sm][sn] = __builtin_amdgcn_mfma_f32_16x16x32_bf16(a1[sm], b1[sn], acc1[sm][sn], 0, 0, 0);
                    acc2[sm][sn] = __builtin_amdgcn_mfma_f32_16x16x32_bf16(a2[sm], b2[sn], acc2[sm][sn], 0, 0, 0);
                }
        }
    }

    const float g2p = sigm(gate_raw2[p]);
#pragma unroll
    for (int sm = 0; sm < 4; ++sm)
#pragma unroll
        for (int sn = 0; sn < 2; ++sn) {
            int gcol = e0 + wn * 32 + sn * 16 + l15;
            float bb = bias2[p * DDOUT + gcol];
            float ob = output_bias[p * DDOUT + gcol];
#pragma unroll
            for (int r = 0; r < 4; ++r) {
                int grow = n0 + wm * 64 + sm * 16 + quad * 4 + r;
                float v1 = acc1[sm][sn][r] + bb;
                float o = sp(sp(v1 * g2p) + acc2[sm][sn][r]) + ob;
                out[(size_t)grow * (NP * DDOUT) + p * DDOUT + gcol] = o;
            }
        }
}

extern "C" void kernel_launch(void* const* d_in, const int* in_sizes, int n_in,
                              void* d_out, int out_size, void* d_ws, size_t ws_size,
                              hipStream_t stream) {
    const float* x           = (const float*)d_in[0];
    const float* phi_raw     = (const float*)d_in[1];
    const float* phi_bias    = (const float*)d_in[2];
    const float* raw_weight2 = (const float*)d_in[3];
    const float* bias2       = (const float*)d_in[4];
    const float* gate_raw2   = (const float*)d_in[5];
    const float* z_weight    = (const float*)d_in[6];
    const float* gate_raw    = (const float*)d_in[7];
    const float* output_bias = (const float*)d_in[8];
    float* out = (float*)d_out;

    u16* ws   = (u16*)d_ws;
    u16* phi  = ws;                                  // 4096*4096 bf16
    u16* wphi = phi + (size_t)4096 * 4096;           // 512*4096
    u16* w2b  = wphi + (size_t)512 * 4096;           // 8*512*512
    u16* zwT  = w2b + (size_t)8 * 512 * 512;         // 8*512*512
    u16* z0   = zwT + (size_t)8 * 512 * 512;         // 8*4096*512
    u16* xb   = z0 + (size_t)8 * 4096 * 512;         // 4096*512
    // split-K=4 bf16 partials in d_out (16.8 MB of 67 MB), consumed by
    // reduce_ep before gemm23 overwrites d_out with the real fp32 output.
    u16* xpart = (u16*)d_out;

    const int n1 = 512 * 4096, n2 = 8 * 512 * 512;
    hipLaunchKernelGGL(prep_sqsp2, dim3((n1 + n2) / 256), dim3(256), 0, stream,
                       phi_raw, wphi, n1, raw_weight2, w2b, n2);
    hipLaunchKernelGGL(prep_zwT, dim3(16, 16, 8), dim3(32, 8), 0, stream, z_weight, zwT);
    hipLaunchKernelGGL(phi_kernel, dim3(8192), dim3(256), 0, stream, x, phi, xb);
    hipLaunchKernelGGL(gemm1p, dim3(512), dim3(512), 0, stream, phi, wphi, xpart);
    hipLaunchKernelGGL(reduce_ep, dim3(2048), dim3(256), 0, stream, xpart, phi_bias, gate_raw, z0);
    hipLaunchKernelGGL(gemm23, dim3(1024), dim3(512), 0, stream,
                       z0, w2b, xb, zwT, bias2, gate_raw2, output_bias, out);
}